// Round 1
// baseline (333.404 us; speedup 1.0000x reference)
//
#include <hip/hip_runtime.h>

typedef unsigned short u16;
using bf16x8 = __bf16 __attribute__((ext_vector_type(8)));
using f32x4  = float  __attribute__((ext_vector_type(4)));

#define B_    4
#define N_    2048
#define N2_   1024
#define DIM_  1024
#define H_    16
#define HD_   64
#define SCALE_ 0.125f

__device__ __forceinline__ u16 f2bf(float f) {
  unsigned u = __float_as_uint(f);
  u += 0x7fffu + ((u >> 16) & 1u);   // round-to-nearest-even
  return (u16)(u >> 16);
}

__device__ __forceinline__ ushort4 f4tobf(float4 v) {
  ushort4 o;
  o.x = f2bf(v.x); o.y = f2bf(v.y); o.z = f2bf(v.z); o.w = f2bf(v.w);
  return o;
}

// ---------------------------------------------------------------------------
// Weight transpose + f32->bf16:  Wt[n][k] = bf16(W[k][n])
// block (32,8), tile 32x32
// ---------------------------------------------------------------------------
__global__ __launch_bounds__(256) void transpose_w(
    const float* __restrict__ W, u16* __restrict__ Wt, int K, int Nc)
{
  __shared__ float t[32][33];
  const int n0 = blockIdx.x * 32, k0 = blockIdx.y * 32;
  const int tx = threadIdx.x, ty = threadIdx.y;
#pragma unroll
  for (int i = 0; i < 4; ++i)
    t[ty + 8*i][tx] = W[(size_t)(k0 + ty + 8*i) * Nc + n0 + tx];
  __syncthreads();
#pragma unroll
  for (int i = 0; i < 4; ++i)
    Wt[(size_t)(n0 + ty + 8*i) * K + k0 + tx] = f2bf(t[tx][ty + 8*i]);
}

// ---------------------------------------------------------------------------
// GEMM  C[M][Nc] = A[M][K] * Bt[Nc][K]^T   (Bt = transposed weight, bf16)
// A: f32 (converted during staging) or bf16, per A_F32.
// OUT_BF16=1: C = bf16(alpha * acc);  OUT_BF16=0: C = f32(acc + bias[c])
// 128x128 tile, BK=32, 256 threads = 4 waves (2x2), 64x64 per wave.
// ---------------------------------------------------------------------------
template<int A_F32, int OUT_BF16>
__global__ __launch_bounds__(256) void gemm_bt(
    const void* __restrict__ Aptr, const u16* __restrict__ Bt,
    float alpha, const float* __restrict__ bias, void* __restrict__ Cptr,
    int M, int Nc, int K)
{
  __shared__ __align__(16) u16 As[128][40];   // +8 pad: 2-way bank alias (free)
  __shared__ __align__(16) u16 Bs[128][40];
  const int tid = threadIdx.x;
  const int m0 = blockIdx.y * 128, n0 = blockIdx.x * 128;
  const int lane = tid & 63, wave = tid >> 6;
  const int wr = wave >> 1, wc = wave & 1;
  const int lr = lane & 15, lg = lane >> 4;
  f32x4 acc[4][4] = {};

  for (int k0 = 0; k0 < K; k0 += 32) {
    float4 fa[4];
    uint4 ua0, ua1, ub0, ub1;
    if (A_F32) {
      const float* A = (const float*)Aptr;
      const int row = tid >> 1, cb = (tid & 1) * 16;
      const float4* src = (const float4*)&A[(size_t)(m0 + row) * K + k0 + cb];
      fa[0] = src[0]; fa[1] = src[1]; fa[2] = src[2]; fa[3] = src[3];
    } else {
      const u16* A = (const u16*)Aptr;
      const int row = tid >> 2, cb = (tid & 3) * 8;
      ua0 = *(const uint4*)&A[(size_t)(m0 + row     ) * K + k0 + cb];
      ua1 = *(const uint4*)&A[(size_t)(m0 + row + 64) * K + k0 + cb];
    }
    {
      const int row = tid >> 2, cb = (tid & 3) * 8;
      ub0 = *(const uint4*)&Bt[(size_t)(n0 + row     ) * K + k0 + cb];
      ub1 = *(const uint4*)&Bt[(size_t)(n0 + row + 64) * K + k0 + cb];
    }
    __syncthreads();   // previous tile fully consumed
    if (A_F32) {
      const int row = tid >> 1, cb = (tid & 1) * 16;
#pragma unroll
      for (int i = 0; i < 4; ++i)
        *(ushort4*)&As[row][cb + 4*i] = f4tobf(fa[i]);
    } else {
      const int row = tid >> 2, cb = (tid & 3) * 8;
      *(uint4*)&As[row     ][cb] = ua0;
      *(uint4*)&As[row + 64][cb] = ua1;
    }
    {
      const int row = tid >> 2, cb = (tid & 3) * 8;
      *(uint4*)&Bs[row     ][cb] = ub0;
      *(uint4*)&Bs[row + 64][cb] = ub1;
    }
    __syncthreads();

    bf16x8 af[4], bfr[4];
#pragma unroll
    for (int m = 0; m < 4; ++m)
      af[m] = *(const bf16x8*)&As[wr*64 + m*16 + lr][lg*8];
#pragma unroll
    for (int n = 0; n < 4; ++n)
      bfr[n] = *(const bf16x8*)&Bs[wc*64 + n*16 + lr][lg*8];
#pragma unroll
    for (int m = 0; m < 4; ++m)
#pragma unroll
      for (int n = 0; n < 4; ++n)
        acc[m][n] = __builtin_amdgcn_mfma_f32_16x16x32_bf16(af[m], bfr[n], acc[m][n], 0, 0, 0);
  }

#pragma unroll
  for (int m = 0; m < 4; ++m)
#pragma unroll
    for (int n = 0; n < 4; ++n)
#pragma unroll
      for (int j = 0; j < 4; ++j) {
        const int r = m0 + wr*64 + m*16 + lg*4 + j;   // row = (lane>>4)*4+reg
        const int c = n0 + wc*64 + n*16 + lr;         // col = lane&15
        const float v = acc[m][n][j] * alpha;
        if (OUT_BF16) ((u16*)Cptr)[(size_t)r * Nc + c] = f2bf(v);
        else          ((float*)Cptr)[(size_t)r * Nc + c] = v + bias[c];
      }
}

// ---------------------------------------------------------------------------
// Flash attention.  Q pre-scaled by SCALE, stored [B,N,DIM] bf16.
// KV [B,N2,2*DIM] bf16 (K at col h*64, V at col 1024+h*64).
// Block: one (b,h) x 64 q-rows; 4 waves x 16 rows.  32-key tiles.
// ---------------------------------------------------------------------------
__global__ __launch_bounds__(256) void attn_kernel(
    const u16* __restrict__ Q, const u16* __restrict__ KV,
    const int* __restrict__ mask, u16* __restrict__ AO)
{
  const int bh = blockIdx.x;            // b*16 + h
  const int qt = blockIdx.y;
  const int b = bh >> 4, h = bh & 15;
  const int tid = threadIdx.x, wave = tid >> 6, lane = tid & 63;
  const int lr = lane & 15, lg = lane >> 4;

  __shared__ __align__(16) u16 Ks[32][72];      // [key][d], +8 pad
  __shared__ __align__(16) u16 Vt[64][40];      // [d][key], +8 pad
  __shared__ __align__(16) u16 Ps[4][16][40];   // per-wave P round-trip

  const int qrow = qt*64 + wave*16 + lr;
  const size_t qoff = ((size_t)b * N_ + qrow) * DIM_ + h * HD_;
  const bf16x8 qf0 = *(const bf16x8*)&Q[qoff +      lg*8];
  const bf16x8 qf1 = *(const bf16x8*)&Q[qoff + 32 + lg*8];

  float mrow[4] = {-1e30f, -1e30f, -1e30f, -1e30f};
  float lsum[4] = {0.f, 0.f, 0.f, 0.f};
  f32x4 oacc[4] = {};

  const int skey = tid >> 3, sch = (tid & 7) * 8;
  const size_t kvbase = (size_t)b * N2_ * 2048 + h * HD_;

  for (int kt = 0; kt < N2_; kt += 32) {
    const size_t rb = kvbase + (size_t)(kt + skey) * 2048;
    const uint4 kvk = *(const uint4*)&KV[rb + sch];
    const uint4 kvv = *(const uint4*)&KV[rb + 1024 + sch];
    __syncthreads();
    *(uint4*)&Ks[skey][sch] = kvk;
    const u16* pv = (const u16*)&kvv;
#pragma unroll
    for (int i = 0; i < 8; ++i) Vt[sch + i][skey] = pv[i];   // transpose V
    __syncthreads();

    // --- QK^T : S[16q x 32key] as two 16x16 accs
    f32x4 s[2] = {};
#pragma unroll
    for (int t = 0; t < 2; ++t) {
      const bf16x8 kf0 = *(const bf16x8*)&Ks[t*16 + lr][     lg*8];
      const bf16x8 kf1 = *(const bf16x8*)&Ks[t*16 + lr][32 + lg*8];
      s[t] = __builtin_amdgcn_mfma_f32_16x16x32_bf16(qf0, kf0, s[t], 0, 0, 0);
      s[t] = __builtin_amdgcn_mfma_f32_16x16x32_bf16(qf1, kf1, s[t], 0, 0, 0);
    }
    const int mk0 = mask[b * N2_ + kt + lr];
    const int mk1 = mask[b * N2_ + kt + 16 + lr];

    // --- online softmax (rows live across 16-lane groups; 4 rows/lane-group)
#pragma unroll
    for (int j = 0; j < 4; ++j) {
      if (!mk0) s[0][j] = -1e30f;
      if (!mk1) s[1][j] = -1e30f;
      float tm = fmaxf(s[0][j], s[1][j]);
#pragma unroll
      for (int d = 1; d < 16; d <<= 1) tm = fmaxf(tm, __shfl_xor(tm, d));
      const float mn = fmaxf(mrow[j], tm);
      const float sc = __expf(mrow[j] - mn);
      s[0][j] = __expf(s[0][j] - mn);
      s[1][j] = __expf(s[1][j] - mn);
      float ps = s[0][j] + s[1][j];
#pragma unroll
      for (int d = 1; d < 16; d <<= 1) ps += __shfl_xor(ps, d);
      lsum[j] = lsum[j] * sc + ps;
      mrow[j] = mn;
#pragma unroll
      for (int n = 0; n < 4; ++n) oacc[n][j] *= sc;
    }

    // --- P (C-layout) -> LDS -> A-layout bf16 fragment
#pragma unroll
    for (int t = 0; t < 2; ++t)
#pragma unroll
      for (int j = 0; j < 4; ++j)
        Ps[wave][lg*4 + j][t*16 + lr] = f2bf(s[t][j]);
    __syncthreads();

    const bf16x8 pf = *(const bf16x8*)&Ps[wave][lr][lg*8];
#pragma unroll
    for (int n = 0; n < 4; ++n) {
      const bf16x8 vf = *(const bf16x8*)&Vt[n*16 + lr][lg*8];
      oacc[n] = __builtin_amdgcn_mfma_f32_16x16x32_bf16(pf, vf, oacc[n], 0, 0, 0);
    }
  }

#pragma unroll
  for (int n = 0; n < 4; ++n)
#pragma unroll
    for (int j = 0; j < 4; ++j) {
      const int q = qt*64 + wave*16 + lg*4 + j;
      const int d = n*16 + lr;
      const float v = oacc[n][j] / lsum[j];
      AO[((size_t)b * N_ + q) * DIM_ + h * HD_ + d] = f2bf(v);
    }
}

// ---------------------------------------------------------------------------
extern "C" void kernel_launch(void* const* d_in, const int* in_sizes, int n_in,
                              void* d_out, int out_size, void* d_ws, size_t ws_size,
                              hipStream_t stream)
{
  const float* x     = (const float*)d_in[0];
  const float* y     = (const float*)d_in[1];
  const int*   pad   = (const int*)  d_in[2];
  const float* Wq    = (const float*)d_in[3];
  const float* Wkv   = (const float*)d_in[4];
  const float* Wproj = (const float*)d_in[5];
  const float* bproj = (const float*)d_in[6];

  char* ws = (char*)d_ws;
  u16* WqT    = (u16*)(ws);                    // 2 MB  [1024][1024]
  u16* WkvT   = (u16*)(ws + (size_t)( 2<<20)); // 4 MB  [2048][1024]
  u16* WprojT = (u16*)(ws + (size_t)( 6<<20)); // 2 MB  [1024][1024]
  u16* Qb     = (u16*)(ws + (size_t)( 8<<20)); // 16 MB [B,N,DIM]  (pre-scaled)
  u16* KVb    = (u16*)(ws + (size_t)(24<<20)); // 16 MB [B,N2,2*DIM]
  u16* AOb    = (u16*)(ws + (size_t)(40<<20)); // 16 MB [B,N,DIM]
  // total: 56 MB

  const dim3 tb(32, 8);
  transpose_w<<<dim3(32, 32), tb, 0, stream>>>(Wq,    WqT,    1024, 1024);
  transpose_w<<<dim3(64, 32), tb, 0, stream>>>(Wkv,   WkvT,   1024, 2048);
  transpose_w<<<dim3(32, 32), tb, 0, stream>>>(Wproj, WprojT, 1024, 1024);

  // Q = (x @ Wq) * SCALE            [8192 x 1024]
  gemm_bt<1, 1><<<dim3( 8, 64), 256, 0, stream>>>(x, WqT, SCALE_, nullptr, Qb, 8192, 1024, 1024);
  // KV = y @ Wkv                    [4096 x 2048]
  gemm_bt<1, 1><<<dim3(16, 32), 256, 0, stream>>>(y, WkvT, 1.0f, nullptr, KVb, 4096, 2048, 1024);
  // flash attention -> AO           [8192 x 1024]
  attn_kernel<<<dim3(64, 32), 256, 0, stream>>>(Qb, KVb, pad, AOb);
  // out = AO @ Wproj + bproj        [8192 x 1024] f32
  gemm_bt<0, 0><<<dim3( 8, 64), 256, 0, stream>>>(AOb, WprojT, 1.0f, bproj, d_out, 8192, 1024, 1024);
}

// Round 6
// 221.356 us; speedup vs baseline: 1.5062x; 1.5062x over previous
//
#include <hip/hip_runtime.h>

typedef unsigned short u16;
typedef unsigned int   u32;
using bf16x8 = __bf16 __attribute__((ext_vector_type(8)));
using f32x4  = float  __attribute__((ext_vector_type(4)));
using f32x16 = float  __attribute__((ext_vector_type(16)));
using u32x2  = u32    __attribute__((ext_vector_type(2)));

#define B_    4
#define N_    2048
#define N2_   1024
#define DIM_  1024
#define H_    16
#define HD_   64
#define SCALE_ 0.125f
#define LOG2E_ 1.4426950408889634f

union PU { u32 w[4]; bf16x8 v; };

__device__ __forceinline__ u16 f2bf(float f) {
  unsigned u = __float_as_uint(f);
  u += 0x7fffu + ((u >> 16) & 1u);   // round-to-nearest-even
  return (u16)(u >> 16);
}

__device__ __forceinline__ u32 packbf(float lo, float hi) {
  return (u32)f2bf(lo) | ((u32)f2bf(hi) << 16);   // lo -> bits[15:0]
}

__device__ __forceinline__ ushort4 f4tobf(float4 v) {
  ushort4 o;
  o.x = f2bf(v.x); o.y = f2bf(v.y); o.z = f2bf(v.z); o.w = f2bf(v.w);
  return o;
}

// combine value with partner lane (lane ^ 32) — verified shfl path
__device__ __forceinline__ float pair_max(float x) {
  return fmaxf(x, __shfl_xor(x, 32));
}
__device__ __forceinline__ float pair_sum(float x) {
  return x + __shfl_xor(x, 32);
}

// ---------------------------------------------------------------------------
// Weight transpose + f32->bf16:  Wt[n][k] = bf16(W[k][n])
// ---------------------------------------------------------------------------
__global__ __launch_bounds__(256) void transpose_w(
    const float* __restrict__ W, u16* __restrict__ Wt, int K, int Nc)
{
  __shared__ float t[32][33];
  const int n0 = blockIdx.x * 32, k0 = blockIdx.y * 32;
  const int tx = threadIdx.x, ty = threadIdx.y;
#pragma unroll
  for (int i = 0; i < 4; ++i)
    t[ty + 8*i][tx] = W[(size_t)(k0 + ty + 8*i) * Nc + n0 + tx];
  __syncthreads();
#pragma unroll
  for (int i = 0; i < 4; ++i)
    Wt[(size_t)(n0 + ty + 8*i) * K + k0 + tx] = f2bf(t[tx][ty + 8*i]);
}

// ---------------------------------------------------------------------------
// V transpose: Vt[(b,h), d, key] = KV[b, key, 1024 + h*64 + d]
// ---------------------------------------------------------------------------
__global__ __launch_bounds__(256) void transpose_v(
    const u16* __restrict__ KV, u16* __restrict__ Vt)
{
  __shared__ u16 t[32][34];
  const int k0 = blockIdx.x * 32, d0 = blockIdx.y * 32, bh = blockIdx.z;
  const int b = bh >> 4, h = bh & 15;
  const int tx = threadIdx.x, ty = threadIdx.y;
#pragma unroll
  for (int i = 0; i < 4; ++i)
    t[ty + 8*i][tx] = KV[((size_t)(b*N2_ + k0 + ty + 8*i))*2048 + 1024 + h*64 + d0 + tx];
  __syncthreads();
#pragma unroll
  for (int i = 0; i < 4; ++i)
    Vt[((size_t)bh*64 + d0 + ty + 8*i)*N2_ + k0 + tx] = t[tx][ty + 8*i];
}

// ---------------------------------------------------------------------------
// GEMM  C[M][Nc] = A[M][K] * Bt[Nc][K]^T   (Bt = transposed weight, bf16)
// ---------------------------------------------------------------------------
template<int A_F32, int OUT_BF16>
__global__ __launch_bounds__(256) void gemm_bt(
    const void* __restrict__ Aptr, const u16* __restrict__ Bt,
    float alpha, const float* __restrict__ bias, void* __restrict__ Cptr,
    int M, int Nc, int K)
{
  __shared__ __align__(16) u16 As[128][40];
  __shared__ __align__(16) u16 Bs[128][40];
  const int tid = threadIdx.x;
  const int m0 = blockIdx.y * 128, n0 = blockIdx.x * 128;
  const int lane = tid & 63, wave = tid >> 6;
  const int wr = wave >> 1, wc = wave & 1;
  const int lr = lane & 15, lg = lane >> 4;
  f32x4 acc[4][4] = {};

  for (int k0 = 0; k0 < K; k0 += 32) {
    float4 fa[4];
    uint4 ua0, ua1, ub0, ub1;
    if (A_F32) {
      const float* A = (const float*)Aptr;
      const int row = tid >> 1, cb = (tid & 1) * 16;
      const float4* src = (const float4*)&A[(size_t)(m0 + row) * K + k0 + cb];
      fa[0] = src[0]; fa[1] = src[1]; fa[2] = src[2]; fa[3] = src[3];
    } else {
      const u16* A = (const u16*)Aptr;
      const int row = tid >> 2, cb = (tid & 3) * 8;
      ua0 = *(const uint4*)&A[(size_t)(m0 + row     ) * K + k0 + cb];
      ua1 = *(const uint4*)&A[(size_t)(m0 + row + 64) * K + k0 + cb];
    }
    {
      const int row = tid >> 2, cb = (tid & 3) * 8;
      ub0 = *(const uint4*)&Bt[(size_t)(n0 + row     ) * K + k0 + cb];
      ub1 = *(const uint4*)&Bt[(size_t)(n0 + row + 64) * K + k0 + cb];
    }
    __syncthreads();
    if (A_F32) {
      const int row = tid >> 1, cb = (tid & 1) * 16;
#pragma unroll
      for (int i = 0; i < 4; ++i)
        *(ushort4*)&As[row][cb + 4*i] = f4tobf(fa[i]);
    } else {
      const int row = tid >> 2, cb = (tid & 3) * 8;
      *(uint4*)&As[row     ][cb] = ua0;
      *(uint4*)&As[row + 64][cb] = ua1;
    }
    {
      const int row = tid >> 2, cb = (tid & 3) * 8;
      *(uint4*)&Bs[row     ][cb] = ub0;
      *(uint4*)&Bs[row + 64][cb] = ub1;
    }
    __syncthreads();

    bf16x8 af[4], bfr[4];
#pragma unroll
    for (int m = 0; m < 4; ++m)
      af[m] = *(const bf16x8*)&As[wr*64 + m*16 + lr][lg*8];
#pragma unroll
    for (int n = 0; n < 4; ++n)
      bfr[n] = *(const bf16x8*)&Bs[wc*64 + n*16 + lr][lg*8];
#pragma unroll
    for (int m = 0; m < 4; ++m)
#pragma unroll
      for (int n = 0; n < 4; ++n)
        acc[m][n] = __builtin_amdgcn_mfma_f32_16x16x32_bf16(af[m], bfr[n], acc[m][n], 0, 0, 0);
  }

#pragma unroll
  for (int m = 0; m < 4; ++m)
#pragma unroll
    for (int n = 0; n < 4; ++n)
#pragma unroll
      for (int j = 0; j < 4; ++j) {
        const int r = m0 + wr*64 + m*16 + lg*4 + j;
        const int c = n0 + wc*64 + n*16 + lr;
        const float v = acc[m][n][j] * alpha;
        if (OUT_BF16) ((u16*)Cptr)[(size_t)r * Nc + c] = f2bf(v);
        else          ((float*)Cptr)[(size_t)r * Nc + c] = v + bias[c];
      }
}

// ---------------------------------------------------------------------------
// Flash attention, swapped-QK^T 32x32 structure, P via per-wave LDS roundtrip.
// NO unverified instructions: packing via f2bf bit-ops, cross-half combine
// via __shfl_xor.  Q pre-scaled by SCALE*log2e.  8 waves x 32 q-rows, KVBLK=64.
// ---------------------------------------------------------------------------
#define QKSTEP(S, QF) { \
    const int c_ = (((S)*2 + hi) ^ x7) * 8; \
    const bf16x8 ka_ = *(const bf16x8*)&Ks[lq*64 + c_]; \
    const bf16x8 kb_ = *(const bf16x8*)&Ks[(32+lq)*64 + c_]; \
    s0 = __builtin_amdgcn_mfma_f32_32x32x16_bf16(ka_, QF, s0, 0, 0, 0); \
    s1 = __builtin_amdgcn_mfma_f32_32x32x16_bf16(kb_, QF, s1, 0, 0, 0); }

__global__ __launch_bounds__(512) void attn2(
    const u16* __restrict__ Q, const u16* __restrict__ KV,
    const u16* __restrict__ Vt, const int* __restrict__ pad,
    u16* __restrict__ AO)
{
  const int qt = blockIdx.x, bh = blockIdx.y;
  const int b = bh >> 4, h = bh & 15;
  const int tid = threadIdx.x;
  const int wave = tid >> 6, lane = tid & 63;
  const int lq = lane & 31, hi = lane >> 5;
  const int x7 = lq & 7;

  __shared__ __align__(16) u16 Ks[64*64];
  __shared__ __align__(16) u16 Vs[64*64];
  __shared__ __align__(16) u32 Ps[8][32][36];   // per-wave P roundtrip (u32 view)
  __shared__ float bias[N2_];

  for (int i = tid; i < N2_; i += 512)
    bias[i] = pad[b*N2_ + i] ? 0.f : -30000.f;
  __syncthreads();

  const int qrow = qt*256 + wave*32 + lq;
  const size_t qbase = ((size_t)b*N_ + qrow)*DIM_ + h*HD_;
  const bf16x8 qf0 = *(const bf16x8*)&Q[qbase +  0 + hi*8];
  const bf16x8 qf1 = *(const bf16x8*)&Q[qbase + 16 + hi*8];
  const bf16x8 qf2 = *(const bf16x8*)&Q[qbase + 32 + hi*8];
  const bf16x8 qf3 = *(const bf16x8*)&Q[qbase + 48 + hi*8];

  f32x16 o0 = {}, o1 = {};
  float mrun = -1e30f, lsum = 0.f;

  const int srow = tid >> 3, schk = tid & 7;
  const int swz = ((schk ^ (srow & 7))) * 8;
  const size_t kgbase = ((size_t)b*N2_)*2048 + h*HD_;
  const size_t vgbase = ((size_t)bh*64 + srow)*N2_;
  u32 (*pw)[36] = Ps[wave];

  for (int kt = 0; kt < N2_; kt += 64) {
    const uint4 kw = *(const uint4*)&KV[kgbase + (size_t)(kt + srow)*2048 + schk*8];
    const uint4 vw = *(const uint4*)&Vt[vgbase + kt + schk*8];

    // bias-initialized score accumulators (mask folded into MFMA C-input)
    // C/D layout: col=lane&31 (query), key=(reg&3)+8*(reg>>2)+4*hi
    f32x16 s0, s1;
#pragma unroll
    for (int g = 0; g < 4; ++g) {
      const f32x4 b0 = *(const f32x4*)&bias[kt +      8*g + 4*hi];
      const f32x4 b1 = *(const f32x4*)&bias[kt + 32 + 8*g + 4*hi];
#pragma unroll
      for (int j = 0; j < 4; ++j) { s0[4*g+j] = b0[j]; s1[4*g+j] = b1[j]; }
    }

    __syncthreads();
    *(uint4*)&Ks[srow*64 + swz] = kw;
    *(uint4*)&Vs[srow*64 + swz] = vw;
    __syncthreads();

    QKSTEP(0, qf0); QKSTEP(1, qf1); QKSTEP(2, qf2); QKSTEP(3, qf3);

    // row max over this tile (32 regs in-lane + partner)
    f32x16 mx;
#pragma unroll
    for (int r = 0; r < 16; ++r) mx[r] = fmaxf(s0[r], s1[r]);
#pragma unroll
    for (int d = 8; d >= 1; d >>= 1)
#pragma unroll
      for (int r = 0; r < 8; ++r) if (r < d) mx[r] = fmaxf(mx[r], mx[r + d]);
    const float tmax = pair_max(mx[0]);

    // classic online-softmax rescale (every tile)
    const float mn = fmaxf(mrun, tmax);
    const float sc = exp2f(mrun - mn);
    mrun = mn;
    lsum *= sc;
#pragma unroll
    for (int r = 0; r < 16; ++r) { o0[r] *= sc; o1[r] *= sc; }

    // P = exp2(S - m)  (log2e folded into Q scaling)
#pragma unroll
    for (int r = 0; r < 16; ++r) {
      s0[r] = exp2f(s0[r] - mrun);
      s1[r] = exp2f(s1[r] - mrun);
    }
    f32x16 sm;
#pragma unroll
    for (int r = 0; r < 16; ++r) sm[r] = s0[r] + s1[r];
#pragma unroll
    for (int d = 8; d >= 1; d >>= 1)
#pragma unroll
      for (int r = 0; r < 8; ++r) if (r < d) sm[r] += sm[r + d];
    lsum += pair_sum(sm[0]);

    // --- P -> per-wave LDS [query][key-pair] as u32 (bf16 pairs)
    // s?[reg] holds key = (reg&3) + 8*(reg>>2) + 4*hi (+32 for s1), query lq
#pragma unroll
    for (int g = 0; g < 4; ++g) {
      pw[lq][     4*g + 2*hi    ] = packbf(s0[4*g+0], s0[4*g+1]);
      pw[lq][     4*g + 2*hi + 1] = packbf(s0[4*g+2], s0[4*g+3]);
      pw[lq][16 + 4*g + 2*hi    ] = packbf(s1[4*g+0], s1[4*g+1]);
      pw[lq][16 + 4*g + 2*hi + 1] = packbf(s1[4*g+2], s1[4*g+3]);
    }
    asm volatile("" ::: "memory");   // same-wave RAW; keep compiler honest

    // --- PV: B-frag = 8 contiguous keys of own query row (u32 reads, union view)
#pragma unroll
    for (int KS = 0; KS < 4; ++KS) {
      PU pu;
#pragma unroll
      for (int j = 0; j < 4; ++j) pu.w[j] = pw[lq][KS*8 + 4*hi + j];
      const int c_ = ((KS*2 + hi) ^ x7) * 8;
      const bf16x8 va = *(const bf16x8*)&Vs[lq*64 + c_];
      const bf16x8 vb = *(const bf16x8*)&Vs[(32+lq)*64 + c_];
      o0 = __builtin_amdgcn_mfma_f32_32x32x16_bf16(va, pu.v, o0, 0, 0, 0);
      o1 = __builtin_amdgcn_mfma_f32_32x32x16_bf16(vb, pu.v, o1, 0, 0, 0);
    }
  }

  const float rls = 1.f / lsum;
  const size_t obase = ((size_t)b*N_ + qrow)*DIM_ + h*HD_;
#pragma unroll
  for (int g = 0; g < 4; ++g) {
    u32x2 w;
    w[0] = packbf(o0[4*g+0]*rls, o0[4*g+1]*rls);
    w[1] = packbf(o0[4*g+2]*rls, o0[4*g+3]*rls);
    *(u32x2*)&AO[obase + 8*g + 4*hi] = w;
    w[0] = packbf(o1[4*g+0]*rls, o1[4*g+1]*rls);
    w[1] = packbf(o1[4*g+2]*rls, o1[4*g+3]*rls);
    *(u32x2*)&AO[obase + 32 + 8*g + 4*hi] = w;
  }
}

// ---------------------------------------------------------------------------
extern "C" void kernel_launch(void* const* d_in, const int* in_sizes, int n_in,
                              void* d_out, int out_size, void* d_ws, size_t ws_size,
                              hipStream_t stream)
{
  const float* x     = (const float*)d_in[0];
  const float* y     = (const float*)d_in[1];
  const int*   pad   = (const int*)  d_in[2];
  const float* Wq    = (const float*)d_in[3];
  const float* Wkv   = (const float*)d_in[4];
  const float* Wproj = (const float*)d_in[5];
  const float* bproj = (const float*)d_in[6];

  // 56 MB workspace layout (R1-proven size), lifetime-disjoint:
  //   [ 0, 2)  WprojT  [ 2,10) Vtg  [10,12) WqT  [12,16) WkvT
  //   [16,32)  Qb      [32,48) KVb  [48,56) AOb
  char* ws = (char*)d_ws;
  u16* WprojT = (u16*)(ws);
  u16* Vtg    = (u16*)(ws + (size_t)( 2<<20));
  u16* WqT    = (u16*)(ws + (size_t)(10<<20));
  u16* WkvT   = (u16*)(ws + (size_t)(12<<20));
  u16* Qb     = (u16*)(ws + (size_t)(16<<20));
  u16* KVb    = (u16*)(ws + (size_t)(32<<20));
  u16* AOb    = (u16*)(ws + (size_t)(48<<20));

  const dim3 tb(32, 8);
  transpose_w<<<dim3(32, 32), tb, 0, stream>>>(Wq,    WqT,    1024, 1024);
  transpose_w<<<dim3(64, 32), tb, 0, stream>>>(Wkv,   WkvT,   1024, 2048);
  transpose_w<<<dim3(32, 32), tb, 0, stream>>>(Wproj, WprojT, 1024, 1024);

  gemm_bt<1, 1><<<dim3( 8, 64), 256, 0, stream>>>(x, WqT, SCALE_ * LOG2E_, nullptr, Qb, 8192, 1024, 1024);
  gemm_bt<1, 1><<<dim3(16, 32), 256, 0, stream>>>(y, WkvT, 1.0f, nullptr, KVb, 4096, 2048, 1024);
  transpose_v<<<dim3(32, 2, 64), tb, 0, stream>>>(KVb, Vtg);
  attn2<<<dim3(8, 64), 512, 0, stream>>>(Qb, KVb, Vtg, pad, AOb);
  gemm_bt<0, 0><<<dim3( 8, 64), 256, 0, stream>>>(AOb, WprojT, 1.0f, bproj, d_out, 8192, 1024, 1024);
}

// Round 7
// 173.412 us; speedup vs baseline: 1.9226x; 1.2765x over previous
//
#include <hip/hip_runtime.h>

typedef unsigned short u16;
typedef unsigned int   u32;
using bf16x8 = __bf16 __attribute__((ext_vector_type(8)));
using f32x4  = float  __attribute__((ext_vector_type(4)));
using f32x16 = float  __attribute__((ext_vector_type(16)));
using u32x2  = u32    __attribute__((ext_vector_type(2)));

#define B_    4
#define N_    2048
#define N2_   1024
#define DIM_  1024
#define H_    16
#define HD_   64
#define SCALE_ 0.125f
#define LOG2E_ 1.4426950408889634f

union PU { u32 w[4]; bf16x8 v; };

__device__ __forceinline__ u16 f2bf(float f) {
  unsigned u = __float_as_uint(f);
  u += 0x7fffu + ((u >> 16) & 1u);   // round-to-nearest-even
  return (u16)(u >> 16);
}

// compiler-generated bf16 pack (RNE) — layout-safe, fast (cvt_pk)
__device__ __forceinline__ u32 packbf(float lo, float hi) {
  union { __bf16 b[2]; u32 u; } c;
  c.b[0] = (__bf16)lo; c.b[1] = (__bf16)hi;
  return c.u;
}

__device__ __forceinline__ float pair_max(float x) { return fmaxf(x, __shfl_xor(x, 32)); }
__device__ __forceinline__ float pair_sum(float x) { return x + __shfl_xor(x, 32); }

// async global->LDS, 16B per lane; lds base must be wave-uniform
__device__ __forceinline__ void gload16(const u16* g, u16* l) {
  __builtin_amdgcn_global_load_lds(
      (const __attribute__((address_space(1))) u32*)g,
      (__attribute__((address_space(3))) u32*)l, 16, 0, 0);
}

// ---------------------------------------------------------------------------
// f32 -> bf16 bulk convert (8 elements/thread)
// ---------------------------------------------------------------------------
__global__ __launch_bounds__(256) void cvt_bf16(
    const float* __restrict__ s, u16* __restrict__ d, int n)
{
  const int i = (blockIdx.x * 256 + threadIdx.x) * 8;
  if (i >= n) return;
  const float4 a = *(const float4*)&s[i];
  const float4 b = *(const float4*)&s[i + 4];
  union { u32 w[4]; uint4 u; } c;
  c.w[0] = packbf(a.x, a.y); c.w[1] = packbf(a.z, a.w);
  c.w[2] = packbf(b.x, b.y); c.w[3] = packbf(b.z, b.w);
  *(uint4*)&d[i] = c.u;
}

// ---------------------------------------------------------------------------
// Weight transpose + f32->bf16:  Wt[n][k] = bf16(W[k][n])
// ---------------------------------------------------------------------------
__global__ __launch_bounds__(256) void transpose_w(
    const float* __restrict__ W, u16* __restrict__ Wt, int K, int Nc)
{
  __shared__ float t[32][33];
  const int n0 = blockIdx.x * 32, k0 = blockIdx.y * 32;
  const int tx = threadIdx.x, ty = threadIdx.y;
#pragma unroll
  for (int i = 0; i < 4; ++i)
    t[ty + 8*i][tx] = W[(size_t)(k0 + ty + 8*i) * Nc + n0 + tx];
  __syncthreads();
#pragma unroll
  for (int i = 0; i < 4; ++i)
    Wt[(size_t)(n0 + ty + 8*i) * K + k0 + tx] = f2bf(t[tx][ty + 8*i]);
}

// ---------------------------------------------------------------------------
// V transpose: Vt[(b,h), d, key] = Vb[b, key, h*64 + d]   (Vb: [B,N2,1024])
// ---------------------------------------------------------------------------
__global__ __launch_bounds__(256) void transpose_v(
    const u16* __restrict__ Vb, u16* __restrict__ Vt)
{
  __shared__ u16 t[32][34];
  const int k0 = blockIdx.x * 32, d0 = blockIdx.y * 32, bh = blockIdx.z;
  const int b = bh >> 4, h = bh & 15;
  const int tx = threadIdx.x, ty = threadIdx.y;
#pragma unroll
  for (int i = 0; i < 4; ++i)
    t[ty + 8*i][tx] = Vb[((size_t)(b*N2_ + k0 + ty + 8*i))*1024 + h*64 + d0 + tx];
  __syncthreads();
#pragma unroll
  for (int i = 0; i < 4; ++i)
    Vt[((size_t)bh*64 + d0 + ty + 8*i)*N2_ + k0 + tx] = t[tx][ty + 8*i];
}

// ---------------------------------------------------------------------------
// GEMM  C = A[M][K](bf16) * Bt[N][K]^T (bf16), m97 structure:
// global_load_lds(16B) staging, BK=64, linear LDS[128][64] with XOR chunk
// swizzle (inverse-swizzled global source + swizzled ds_read => conflict-free).
// OUT_BF16=1: C = bf16(alpha*acc), split output at col Nout into C1.
// OUT_BF16=0: C = f32(acc + bias[c]).
// 128x128 tile, 256 threads = 4 waves (2x2), 64x64 per wave.
// ---------------------------------------------------------------------------
template<int OUT_BF16>
__global__ __launch_bounds__(256) void gemm_bt(
    const u16* __restrict__ A, const u16* __restrict__ Bt,
    float alpha, const float* __restrict__ bias,
    void* __restrict__ C0, void* __restrict__ C1, int Nout,
    int M, int K)
{
  __shared__ __align__(16) u16 As[128 * 64];
  __shared__ __align__(16) u16 Bs[128 * 64];
  const int tid = threadIdx.x;
  const int m0 = blockIdx.y * 128, n0 = blockIdx.x * 128;
  const int lane = tid & 63, wave = tid >> 6;
  const int wr = wave >> 1, wc = wave & 1;
  const int lr = lane & 15, lg = lane >> 4;
  f32x4 acc[4][4] = {};

  // staging: lane l covers row (32*wave + 8*i + l>>3), 16B chunk (l&7),
  // global chunk pre-swizzled by ^(row&7) = ^(l>>3)
  const int l8 = lane >> 3;
  const int c8 = ((lane & 7) ^ l8) * 8;
  const u16* ga = &A [(size_t)(m0 + 32*wave + l8) * K + c8];
  const u16* gb = &Bt[(size_t)(n0 + 32*wave + l8) * K + c8];

  for (int k0 = 0; k0 < K; k0 += 64) {
    __syncthreads();   // previous tile fully consumed
#pragma unroll
    for (int i = 0; i < 4; ++i) {
      gload16(ga + (size_t)(8*i)*K + k0, &As[(wave*4 + i) * 512]);
      gload16(gb + (size_t)(8*i)*K + k0, &Bs[(wave*4 + i) * 512]);
    }
    __syncthreads();   // drains vmcnt: tile ready

#pragma unroll
    for (int kk = 0; kk < 2; ++kk) {
      bf16x8 af[4], bfr[4];
#pragma unroll
      for (int m = 0; m < 4; ++m) {
        const int row = wr*64 + m*16 + lr;
        af[m] = *(const bf16x8*)&As[row*64 + (((kk*4 + lg) ^ (row & 7)) * 8)];
      }
#pragma unroll
      for (int n = 0; n < 4; ++n) {
        const int row = wc*64 + n*16 + lr;
        bfr[n] = *(const bf16x8*)&Bs[row*64 + (((kk*4 + lg) ^ (row & 7)) * 8)];
      }
#pragma unroll
      for (int m = 0; m < 4; ++m)
#pragma unroll
        for (int n = 0; n < 4; ++n)
          acc[m][n] = __builtin_amdgcn_mfma_f32_16x16x32_bf16(af[m], bfr[n], acc[m][n], 0, 0, 0);
    }
  }

  int cbase = n0;
  u16* Cb = (u16*)C0;
  if (OUT_BF16 && C1 && n0 >= Nout) { Cb = (u16*)C1; cbase = n0 - Nout; }

#pragma unroll
  for (int m = 0; m < 4; ++m)
#pragma unroll
    for (int n = 0; n < 4; ++n)
#pragma unroll
      for (int j = 0; j < 4; ++j) {
        const int r = m0 + wr*64 + m*16 + lg*4 + j;
        const int c = cbase + wc*64 + n*16 + lr;
        const float v = acc[m][n][j] * alpha;
        if (OUT_BF16) Cb[(size_t)r * Nout + c] = f2bf(v);
        else          ((float*)C0)[(size_t)r * Nout + c] = v + bias[c];
      }
}

// ---------------------------------------------------------------------------
// Flash attention, swapped-QK^T 32x32, P via per-wave LDS roundtrip.
// Q pre-scaled by SCALE*log2e.  Kb [B,N2,1024] bf16, Vt [B*H,64,N2] bf16.
// 8 waves x 32 q-rows, KVBLK=64.  blockIdx.x = bh (XCD locality), .y = qt.
// ---------------------------------------------------------------------------
#define QKSTEP(S, QF) { \
    const int c_ = (((S)*2 + hi) ^ x7) * 8; \
    const bf16x8 ka_ = *(const bf16x8*)&Ks[lq*64 + c_]; \
    const bf16x8 kb_ = *(const bf16x8*)&Ks[(32+lq)*64 + c_]; \
    s0 = __builtin_amdgcn_mfma_f32_32x32x16_bf16(ka_, QF, s0, 0, 0, 0); \
    s1 = __builtin_amdgcn_mfma_f32_32x32x16_bf16(kb_, QF, s1, 0, 0, 0); }

__global__ __launch_bounds__(512) void attn2(
    const u16* __restrict__ Q, const u16* __restrict__ Kb,
    const u16* __restrict__ Vt, const int* __restrict__ pad,
    u16* __restrict__ AO)
{
  const int bh = blockIdx.x, qt = blockIdx.y;
  const int b = bh >> 4, h = bh & 15;
  const int tid = threadIdx.x;
  const int wave = tid >> 6, lane = tid & 63;
  const int lq = lane & 31, hi = lane >> 5;
  const int x7 = lq & 7;

  __shared__ __align__(16) u16 Ks[64*64];
  __shared__ __align__(16) u16 Vs[64*64];
  __shared__ __align__(16) u32 Ps[8][32][36];
  __shared__ float bias[N2_];

  for (int i = tid; i < N2_; i += 512)
    bias[i] = pad[b*N2_ + i] ? 0.f : -30000.f;
  __syncthreads();

  const int qrow = qt*256 + wave*32 + lq;
  const size_t qbase = ((size_t)b*N_ + qrow)*DIM_ + h*HD_;
  const bf16x8 qf0 = *(const bf16x8*)&Q[qbase +  0 + hi*8];
  const bf16x8 qf1 = *(const bf16x8*)&Q[qbase + 16 + hi*8];
  const bf16x8 qf2 = *(const bf16x8*)&Q[qbase + 32 + hi*8];
  const bf16x8 qf3 = *(const bf16x8*)&Q[qbase + 48 + hi*8];

  f32x16 o0 = {}, o1 = {};
  float mrun = -1e30f, lsum = 0.f;

  const int srow = tid >> 3, schk = tid & 7;
  const int swz = ((schk ^ (srow & 7))) * 8;
  const size_t kgbase = (size_t)b*N2_*1024 + h*HD_;
  const size_t vgbase = ((size_t)bh*64 + srow)*N2_;
  u32 (*pw)[36] = Ps[wave];

  for (int kt = 0; kt < N2_; kt += 64) {
    const uint4 kw = *(const uint4*)&Kb[kgbase + (size_t)(kt + srow)*1024 + schk*8];
    const uint4 vw = *(const uint4*)&Vt[vgbase + kt + schk*8];

    // bias-initialized score accs (mask folded into MFMA C-input)
    // C/D layout: col=lane&31 (query), key=(reg&3)+8*(reg>>2)+4*hi
    f32x16 s0, s1;
#pragma unroll
    for (int g = 0; g < 4; ++g) {
      const f32x4 b0 = *(const f32x4*)&bias[kt +      8*g + 4*hi];
      const f32x4 b1 = *(const f32x4*)&bias[kt + 32 + 8*g + 4*hi];
#pragma unroll
      for (int j = 0; j < 4; ++j) { s0[4*g+j] = b0[j]; s1[4*g+j] = b1[j]; }
    }

    __syncthreads();
    *(uint4*)&Ks[srow*64 + swz] = kw;
    *(uint4*)&Vs[srow*64 + swz] = vw;
    __syncthreads();

    __builtin_amdgcn_s_setprio(1);
    QKSTEP(0, qf0); QKSTEP(1, qf1); QKSTEP(2, qf2); QKSTEP(3, qf3);
    __builtin_amdgcn_s_setprio(0);

    // row max over this tile
    f32x16 mx;
#pragma unroll
    for (int r = 0; r < 16; ++r) mx[r] = fmaxf(s0[r], s1[r]);
#pragma unroll
    for (int d = 8; d >= 1; d >>= 1)
#pragma unroll
      for (int r = 0; r < 8; ++r) if (r < d) mx[r] = fmaxf(mx[r], mx[r + d]);
    const float tmax = pair_max(mx[0]);

    // defer-max (T13): skip O-rescale when max grew by < 8 (exp2 headroom 256)
    if (!__all(tmax <= mrun + 8.f)) {
      const float mn = fmaxf(mrun, tmax);
      const float sc = exp2f(mrun - mn);
      mrun = mn;
      lsum *= sc;
#pragma unroll
      for (int r = 0; r < 16; ++r) { o0[r] *= sc; o1[r] *= sc; }
    }

    // P = exp2(S - m)
#pragma unroll
    for (int r = 0; r < 16; ++r) {
      s0[r] = exp2f(s0[r] - mrun);
      s1[r] = exp2f(s1[r] - mrun);
    }
    f32x16 sm;
#pragma unroll
    for (int r = 0; r < 16; ++r) sm[r] = s0[r] + s1[r];
#pragma unroll
    for (int d = 8; d >= 1; d >>= 1)
#pragma unroll
      for (int r = 0; r < 8; ++r) if (r < d) sm[r] += sm[r + d];
    lsum += pair_sum(sm[0]);

    // P -> per-wave LDS (u32 both sides, no cross-wave barrier)
#pragma unroll
    for (int g = 0; g < 4; ++g) {
      pw[lq][     4*g + 2*hi    ] = packbf(s0[4*g+0], s0[4*g+1]);
      pw[lq][     4*g + 2*hi + 1] = packbf(s0[4*g+2], s0[4*g+3]);
      pw[lq][16 + 4*g + 2*hi    ] = packbf(s1[4*g+0], s1[4*g+1]);
      pw[lq][16 + 4*g + 2*hi + 1] = packbf(s1[4*g+2], s1[4*g+3]);
    }
    asm volatile("" ::: "memory");

    // PV
    __builtin_amdgcn_s_setprio(1);
#pragma unroll
    for (int KS = 0; KS < 4; ++KS) {
      PU pu;
#pragma unroll
      for (int j = 0; j < 4; ++j) pu.w[j] = pw[lq][KS*8 + 4*hi + j];
      const int c_ = ((KS*2 + hi) ^ x7) * 8;
      const bf16x8 va = *(const bf16x8*)&Vs[lq*64 + c_];
      const bf16x8 vb = *(const bf16x8*)&Vs[(32+lq)*64 + c_];
      o0 = __builtin_amdgcn_mfma_f32_32x32x16_bf16(va, pu.v, o0, 0, 0, 0);
      o1 = __builtin_amdgcn_mfma_f32_32x32x16_bf16(vb, pu.v, o1, 0, 0, 0);
    }
    __builtin_amdgcn_s_setprio(0);
  }

  const float rls = 1.f / lsum;
  const size_t obase = ((size_t)b*N_ + qrow)*DIM_ + h*HD_;
#pragma unroll
  for (int g = 0; g < 4; ++g) {
    u32x2 w;
    w[0] = packbf(o0[4*g+0]*rls, o0[4*g+1]*rls);
    w[1] = packbf(o0[4*g+2]*rls, o0[4*g+3]*rls);
    *(u32x2*)&AO[obase + 8*g + 4*hi] = w;
    w[0] = packbf(o1[4*g+0]*rls, o1[4*g+1]*rls);
    w[1] = packbf(o1[4*g+2]*rls, o1[4*g+3]*rls);
    *(u32x2*)&AO[obase + 32 + 8*g + 4*hi] = w;
  }
}

// ---------------------------------------------------------------------------
extern "C" void kernel_launch(void* const* d_in, const int* in_sizes, int n_in,
                              void* d_out, int out_size, void* d_ws, size_t ws_size,
                              hipStream_t stream)
{
  const float* x     = (const float*)d_in[0];
  const float* y     = (const float*)d_in[1];
  const int*   pad   = (const int*)  d_in[2];
  const float* Wq    = (const float*)d_in[3];
  const float* Wkv   = (const float*)d_in[4];
  const float* Wproj = (const float*)d_in[5];
  const float* bproj = (const float*)d_in[6];

  // 56 MB workspace, lifetime-disjoint (t0 cvt_x, t1 cvt_y, t2 transposes,
  // t3 Q-gemm, t4 KV-gemm, t5 transpose_v, t6 attn, t7 proj-gemm):
  //   [ 0,16) xb  t0->t3   then  Kb [0,8) t4->t6,  Vb [8,16) t4->t5
  //   [16,24) yb  t1->t4   then  Vtg [16,24) t5->t6
  //   [24,26) WqT t2->t3   [26,30) WkvT t2->t4   [30,32) WprojT t2->t7
  //   [32,48) Qb  t3->t6   [48,56) AOb t6->t7
  char* ws = (char*)d_ws;
  u16* xb     = (u16*)(ws);
  u16* Kb     = (u16*)(ws);
  u16* Vb     = (u16*)(ws + (size_t)( 8<<20));
  u16* yb     = (u16*)(ws + (size_t)(16<<20));
  u16* Vtg    = (u16*)(ws + (size_t)(16<<20));
  u16* WqT    = (u16*)(ws + (size_t)(24<<20));
  u16* WkvT   = (u16*)(ws + (size_t)(26<<20));
  u16* WprojT = (u16*)(ws + (size_t)(30<<20));
  u16* Qb     = (u16*)(ws + (size_t)(32<<20));
  u16* AOb    = (u16*)(ws + (size_t)(48<<20));

  const dim3 tb(32, 8);
  cvt_bf16<<<dim3(4096), 256, 0, stream>>>(x, xb, B_*N_*DIM_);     // t0
  cvt_bf16<<<dim3(2048), 256, 0, stream>>>(y, yb, B_*N2_*DIM_);    // t1
  transpose_w<<<dim3(32, 32), tb, 0, stream>>>(Wq,    WqT,    1024, 1024);
  transpose_w<<<dim3(64, 32), tb, 0, stream>>>(Wkv,   WkvT,   1024, 2048);
  transpose_w<<<dim3(32, 32), tb, 0, stream>>>(Wproj, WprojT, 1024, 1024);

  // Q = (x @ Wq) * SCALE*log2e
  gemm_bt<1><<<dim3( 8, 64), 256, 0, stream>>>(xb, WqT, SCALE_*LOG2E_, nullptr,
                                               Qb, nullptr, 1024, 8192, 1024);
  // [K|V] = y @ Wkv, split into Kb / Vb
  gemm_bt<1><<<dim3(16, 32), 256, 0, stream>>>(yb, WkvT, 1.0f, nullptr,
                                               Kb, Vb, 1024, 4096, 1024);
  transpose_v<<<dim3(32, 2, 64), tb, 0, stream>>>(Vb, Vtg);
  attn2<<<dim3(64, 8), 512, 0, stream>>>(Qb, Kb, Vtg, pad, AOb);
  // out = AO @ Wproj + bproj  (f32)
  gemm_bt<0><<<dim3( 8, 64), 256, 0, stream>>>(AOb, WprojT, 1.0f, bproj,
                                               d_out, nullptr, 1024, 8192, 1024);
}

// Round 8
// 169.989 us; speedup vs baseline: 1.9613x; 1.0201x over previous
//
#include <hip/hip_runtime.h>

typedef unsigned short u16;
typedef unsigned int   u32;
using bf16x8 = __bf16 __attribute__((ext_vector_type(8)));
using f32x4  = float  __attribute__((ext_vector_type(4)));
using f32x16 = float  __attribute__((ext_vector_type(16)));
using u32x2  = u32    __attribute__((ext_vector_type(2)));

#define B_    4
#define N_    2048
#define N2_   1024
#define DIM_  1024
#define H_    16
#define HD_   64
#define SCALE_ 0.125f
#define LOG2E_ 1.4426950408889634f

union PU { u32 w[4]; bf16x8 v; };

__device__ __forceinline__ u16 f2bf(float f) {
  unsigned u = __float_as_uint(f);
  u += 0x7fffu + ((u >> 16) & 1u);   // round-to-nearest-even
  return (u16)(u >> 16);
}

// compiler-generated bf16 pack (RNE) — layout-safe
__device__ __forceinline__ u32 packbf(float lo, float hi) {
  union { __bf16 b[2]; u32 u; } c;
  c.b[0] = (__bf16)lo; c.b[1] = (__bf16)hi;
  return c.u;
}

__device__ __forceinline__ float pair_max(float x) { return fmaxf(x, __shfl_xor(x, 32)); }
__device__ __forceinline__ float pair_sum(float x) { return x + __shfl_xor(x, 32); }

// async global->LDS, 16B per lane; lds base must be wave-uniform
__device__ __forceinline__ void gload16(const u16* g, u16* l) {
  __builtin_amdgcn_global_load_lds(
      (const __attribute__((address_space(1))) u32*)g,
      (__attribute__((address_space(3))) u32*)l, 16, 0, 0);
}

// ---------------------------------------------------------------------------
// f32 -> bf16 bulk convert (8 elements/thread)
// ---------------------------------------------------------------------------
__global__ __launch_bounds__(256) void cvt_bf16(
    const float* __restrict__ s, u16* __restrict__ d, int n)
{
  const int i = (blockIdx.x * 256 + threadIdx.x) * 8;
  if (i >= n) return;
  const float4 a = *(const float4*)&s[i];
  const float4 b = *(const float4*)&s[i + 4];
  union { u32 w[4]; uint4 u; } c;
  c.w[0] = packbf(a.x, a.y); c.w[1] = packbf(a.z, a.w);
  c.w[2] = packbf(b.x, b.y); c.w[3] = packbf(b.z, b.w);
  *(uint4*)&d[i] = c.u;
}

// ---------------------------------------------------------------------------
// Weight transpose + f32->bf16:  Wt[n][k] = bf16(W[k][n])
// ---------------------------------------------------------------------------
__global__ __launch_bounds__(256) void transpose_w(
    const float* __restrict__ W, u16* __restrict__ Wt, int K, int Nc)
{
  __shared__ float t[32][33];
  const int n0 = blockIdx.x * 32, k0 = blockIdx.y * 32;
  const int tx = threadIdx.x, ty = threadIdx.y;
#pragma unroll
  for (int i = 0; i < 4; ++i)
    t[ty + 8*i][tx] = W[(size_t)(k0 + ty + 8*i) * Nc + n0 + tx];
  __syncthreads();
#pragma unroll
  for (int i = 0; i < 4; ++i)
    Wt[(size_t)(n0 + ty + 8*i) * K + k0 + tx] = f2bf(t[tx][ty + 8*i]);
}

// ---------------------------------------------------------------------------
// V transpose: Vt[(b,h), d, key] = Vb[b, key, h*64 + d]   (Vb: [B,N2,1024])
// ---------------------------------------------------------------------------
__global__ __launch_bounds__(256) void transpose_v(
    const u16* __restrict__ Vb, u16* __restrict__ Vt)
{
  __shared__ u16 t[32][34];
  const int k0 = blockIdx.x * 32, d0 = blockIdx.y * 32, bh = blockIdx.z;
  const int b = bh >> 4, h = bh & 15;
  const int tx = threadIdx.x, ty = threadIdx.y;
#pragma unroll
  for (int i = 0; i < 4; ++i)
    t[ty + 8*i][tx] = Vb[((size_t)(b*N2_ + k0 + ty + 8*i))*1024 + h*64 + d0 + tx];
  __syncthreads();
#pragma unroll
  for (int i = 0; i < 4; ++i)
    Vt[((size_t)bh*64 + d0 + ty + 8*i)*N2_ + k0 + tx] = t[tx][ty + 8*i];
}

// ---------------------------------------------------------------------------
// GEMM  C = A[M][K](bf16) * Bt[N][K]^T (bf16):
// global_load_lds(16B) staging, BK=64, DOUBLE-buffered LDS, one barrier/tile
// ("minimum 2-phase": issue STAGE(next) -> ds_read+MFMA(cur) -> syncthreads).
// LDS XOR chunk swizzle both-sides (inverse-swizzled source + swizzled read).
// 128x128 tile, 256 threads = 4 waves (2x2), 64x64 per wave.
// ---------------------------------------------------------------------------
template<int OUT_BF16>
__global__ __launch_bounds__(256) void gemm_bt(
    const u16* __restrict__ A, const u16* __restrict__ Bt,
    float alpha, const float* __restrict__ bias,
    void* __restrict__ C0, void* __restrict__ C1, int Nout,
    int M, int K)
{
  __shared__ __align__(16) u16 As[2][128 * 64];
  __shared__ __align__(16) u16 Bs[2][128 * 64];
  const int tid = threadIdx.x;
  const int m0 = blockIdx.y * 128, n0 = blockIdx.x * 128;
  const int lane = tid & 63, wave = tid >> 6;
  const int wr = wave >> 1, wc = wave & 1;
  const int lr = lane & 15, lg = lane >> 4;
  f32x4 acc[4][4] = {};

  // staging: lane l covers row (32*wave + 8*i + l>>3), 16B chunk (l&7),
  // global chunk pre-swizzled by ^(l>>3) so LDS dest stays linear
  const int l8 = lane >> 3;
  const int c8 = ((lane & 7) ^ l8) * 8;
  const u16* ga = &A [(size_t)(m0 + 32*wave + l8) * K + c8];
  const u16* gb = &Bt[(size_t)(n0 + 32*wave + l8) * K + c8];

#define STAGE(buf, k0) { \
    _Pragma("unroll") \
    for (int i = 0; i < 4; ++i) { \
      gload16(ga + (size_t)(8*i)*K + (k0), &As[buf][(wave*4 + i) * 512]); \
      gload16(gb + (size_t)(8*i)*K + (k0), &Bs[buf][(wave*4 + i) * 512]); \
    } }

  STAGE(0, 0);
  __syncthreads();              // implicit vmcnt(0): tile 0 ready
  int cur = 0;
  const int NT = K >> 6;
  for (int t = 0; t < NT; ++t) {
    if (t + 1 < NT) STAGE(cur ^ 1, (t + 1) * 64);   // issue early, lands under MFMA
#pragma unroll
    for (int kk = 0; kk < 2; ++kk) {
      bf16x8 af[4], bfr[4];
#pragma unroll
      for (int m = 0; m < 4; ++m) {
        const int row = wr*64 + m*16 + lr;
        af[m] = *(const bf16x8*)&As[cur][row*64 + (((kk*4 + lg) ^ (row & 7)) * 8)];
      }
#pragma unroll
      for (int n = 0; n < 4; ++n) {
        const int row = wc*64 + n*16 + lr;
        bfr[n] = *(const bf16x8*)&Bs[cur][row*64 + (((kk*4 + lg) ^ (row & 7)) * 8)];
      }
      __builtin_amdgcn_s_setprio(1);
#pragma unroll
      for (int m = 0; m < 4; ++m)
#pragma unroll
        for (int n = 0; n < 4; ++n)
          acc[m][n] = __builtin_amdgcn_mfma_f32_16x16x32_bf16(af[m], bfr[n], acc[m][n], 0, 0, 0);
      __builtin_amdgcn_s_setprio(0);
    }
    __syncthreads();            // drains stage loads + all waves done with cur
    cur ^= 1;
  }
#undef STAGE

  int cbase = n0;
  u16* Cb = (u16*)C0;
  if (OUT_BF16 && C1 && n0 >= Nout) { Cb = (u16*)C1; cbase = n0 - Nout; }

#pragma unroll
  for (int m = 0; m < 4; ++m)
#pragma unroll
    for (int n = 0; n < 4; ++n)
#pragma unroll
      for (int j = 0; j < 4; ++j) {
        const int r = m0 + wr*64 + m*16 + lg*4 + j;
        const int c = cbase + wc*64 + n*16 + lr;
        const float v = acc[m][n][j] * alpha;
        if (OUT_BF16) Cb[(size_t)r * Nout + c] = f2bf(v);
        else          ((float*)C0)[(size_t)r * Nout + c] = v + bias[c];
      }
}

// ---------------------------------------------------------------------------
// Flash attention, swapped-QK^T 32x32, P via per-wave LDS roundtrip.
// __launch_bounds__(512,4): 128-VGPR budget matches LDS-limited 2 blocks/CU.
// T14: K/V tile loads issued right after the staging barrier, consumed next
// iteration -> HBM/L2 latency hides under QK+softmax+PV.
// Q pre-scaled by SCALE*log2e.  Kb [B,N2,1024] bf16, Vt [B*H,64,N2] bf16.
// 8 waves x 32 q-rows, KVBLK=64.  blockIdx.x = bh (XCD locality), .y = qt.
// ---------------------------------------------------------------------------
#define QKSTEP(S, QF) { \
    const int c_ = (((S)*2 + hi) ^ x7) * 8; \
    const bf16x8 ka_ = *(const bf16x8*)&Ks[lq*64 + c_]; \
    const bf16x8 kb_ = *(const bf16x8*)&Ks[(32+lq)*64 + c_]; \
    s0 = __builtin_amdgcn_mfma_f32_32x32x16_bf16(ka_, QF, s0, 0, 0, 0); \
    s1 = __builtin_amdgcn_mfma_f32_32x32x16_bf16(kb_, QF, s1, 0, 0, 0); }

__global__ __launch_bounds__(512, 4) void attn2(
    const u16* __restrict__ Q, const u16* __restrict__ Kb,
    const u16* __restrict__ Vt, const int* __restrict__ pad,
    u16* __restrict__ AO)
{
  const int bh = blockIdx.x, qt = blockIdx.y;
  const int b = bh >> 4, h = bh & 15;
  const int tid = threadIdx.x;
  const int wave = tid >> 6, lane = tid & 63;
  const int lq = lane & 31, hi = lane >> 5;
  const int x7 = lq & 7;

  __shared__ __align__(16) u16 Ks[64*64];
  __shared__ __align__(16) u16 Vs[64*64];
  __shared__ __align__(16) u32 Ps[8][32][36];
  __shared__ float bias[N2_];

  for (int i = tid; i < N2_; i += 512)
    bias[i] = pad[b*N2_ + i] ? 0.f : -30000.f;
  __syncthreads();

  const int qrow = qt*256 + wave*32 + lq;
  const size_t qbase = ((size_t)b*N_ + qrow)*DIM_ + h*HD_;
  const bf16x8 qf0 = *(const bf16x8*)&Q[qbase +  0 + hi*8];
  const bf16x8 qf1 = *(const bf16x8*)&Q[qbase + 16 + hi*8];
  const bf16x8 qf2 = *(const bf16x8*)&Q[qbase + 32 + hi*8];
  const bf16x8 qf3 = *(const bf16x8*)&Q[qbase + 48 + hi*8];

  f32x16 o0 = {}, o1 = {};
  float mrun = -1e30f, lsum = 0.f;

  const int srow = tid >> 3, schk = tid & 7;
  const int swz = ((schk ^ (srow & 7))) * 8;
  const u16* kptr = &Kb[(size_t)b*N2_*1024 + h*HD_ + (size_t)srow*1024 + schk*8];
  const u16* vptr = &Vt[((size_t)bh*64 + srow)*N2_ + schk*8];
  u32 (*pw)[36] = Ps[wave];

  // prologue: preload tile 0
  uint4 kw = *(const uint4*)kptr;
  uint4 vw = *(const uint4*)vptr;

  for (int kt = 0; kt < N2_; kt += 64) {
    // bias-initialized score accs (mask folded into MFMA C-input)
    // C/D layout: col=lane&31 (query), key=(reg&3)+8*(reg>>2)+4*hi
    f32x16 s0, s1;
#pragma unroll
    for (int g = 0; g < 4; ++g) {
      const f32x4 b0 = *(const f32x4*)&bias[kt +      8*g + 4*hi];
      const f32x4 b1 = *(const f32x4*)&bias[kt + 32 + 8*g + 4*hi];
#pragma unroll
      for (int j = 0; j < 4; ++j) { s0[4*g+j] = b0[j]; s1[4*g+j] = b1[j]; }
    }

    __syncthreads();                       // all waves done reading prev tile
    *(uint4*)&Ks[srow*64 + swz] = kw;
    *(uint4*)&Vs[srow*64 + swz] = vw;
    __syncthreads();                       // tile ready

    if (kt + 64 < N2_) {                   // T14: issue next-tile loads NOW
      kw = *(const uint4*)(kptr + (size_t)(kt + 64)*1024);
      vw = *(const uint4*)(vptr + (kt + 64));
    }

    __builtin_amdgcn_s_setprio(1);
    QKSTEP(0, qf0); QKSTEP(1, qf1); QKSTEP(2, qf2); QKSTEP(3, qf3);
    __builtin_amdgcn_s_setprio(0);

    // row max over this tile
    f32x16 mx;
#pragma unroll
    for (int r = 0; r < 16; ++r) mx[r] = fmaxf(s0[r], s1[r]);
#pragma unroll
    for (int d = 8; d >= 1; d >>= 1)
#pragma unroll
      for (int r = 0; r < 8; ++r) if (r < d) mx[r] = fmaxf(mx[r], mx[r + d]);
    const float tmax = pair_max(mx[0]);

    // defer-max (T13): skip O-rescale when max grew by < 8 (exp2 headroom)
    if (!__all(tmax <= mrun + 8.f)) {
      const float mn = fmaxf(mrun, tmax);
      const float sc = exp2f(mrun - mn);
      mrun = mn;
      lsum *= sc;
#pragma unroll
      for (int r = 0; r < 16; ++r) { o0[r] *= sc; o1[r] *= sc; }
    }

    // P = exp2(S - m)
#pragma unroll
    for (int r = 0; r < 16; ++r) {
      s0[r] = exp2f(s0[r] - mrun);
      s1[r] = exp2f(s1[r] - mrun);
    }
    f32x16 sm;
#pragma unroll
    for (int r = 0; r < 16; ++r) sm[r] = s0[r] + s1[r];
#pragma unroll
    for (int d = 8; d >= 1; d >>= 1)
#pragma unroll
      for (int r = 0; r < 8; ++r) if (r < d) sm[r] += sm[r + d];
    lsum += pair_sum(sm[0]);

    // P -> per-wave LDS (u32 both sides, no cross-wave barrier)
#pragma unroll
    for (int g = 0; g < 4; ++g) {
      pw[lq][     4*g + 2*hi    ] = packbf(s0[4*g+0], s0[4*g+1]);
      pw[lq][     4*g + 2*hi + 1] = packbf(s0[4*g+2], s0[4*g+3]);
      pw[lq][16 + 4*g + 2*hi    ] = packbf(s1[4*g+0], s1[4*g+1]);
      pw[lq][16 + 4*g + 2*hi + 1] = packbf(s1[4*g+2], s1[4*g+3]);
    }
    asm volatile("" ::: "memory");

    // PV
    __builtin_amdgcn_s_setprio(1);
#pragma unroll
    for (int KS = 0; KS < 4; ++KS) {
      PU pu;
#pragma unroll
      for (int j = 0; j < 4; ++j) pu.w[j] = pw[lq][KS*8 + 4*hi + j];
      const int c_ = ((KS*2 + hi) ^ x7) * 8;
      const bf16x8 va = *(const bf16x8*)&Vs[lq*64 + c_];
      const bf16x8 vb = *(const bf16x8*)&Vs[(32+lq)*64 + c_];
      o0 = __builtin_amdgcn_mfma_f32_32x32x16_bf16(va, pu.v, o0, 0, 0, 0);
      o1 = __builtin_amdgcn_mfma_f32_32x32x16_bf16(vb, pu.v, o1, 0, 0, 0);
    }
    __builtin_amdgcn_s_setprio(0);
  }

  const float rls = 1.f / lsum;
  const size_t obase = ((size_t)b*N_ + qrow)*DIM_ + h*HD_;
#pragma unroll
  for (int g = 0; g < 4; ++g) {
    u32x2 w;
    w[0] = packbf(o0[4*g+0]*rls, o0[4*g+1]*rls);
    w[1] = packbf(o0[4*g+2]*rls, o0[4*g+3]*rls);
    *(u32x2*)&AO[obase + 8*g + 4*hi] = w;
    w[0] = packbf(o1[4*g+0]*rls, o1[4*g+1]*rls);
    w[1] = packbf(o1[4*g+2]*rls, o1[4*g+3]*rls);
    *(u32x2*)&AO[obase + 32 + 8*g + 4*hi] = w;
  }
}

// ---------------------------------------------------------------------------
extern "C" void kernel_launch(void* const* d_in, const int* in_sizes, int n_in,
                              void* d_out, int out_size, void* d_ws, size_t ws_size,
                              hipStream_t stream)
{
  const float* x     = (const float*)d_in[0];
  const float* y     = (const float*)d_in[1];
  const int*   pad   = (const int*)  d_in[2];
  const float* Wq    = (const float*)d_in[3];
  const float* Wkv   = (const float*)d_in[4];
  const float* Wproj = (const float*)d_in[5];
  const float* bproj = (const float*)d_in[6];

  // 56 MB workspace, lifetime-disjoint:
  //   [ 0,16) xb  t0->t3   then  Kb [0,8) t4->t6,  Vb [8,16) t4->t5
  //   [16,24) yb  t1->t4   then  Vtg [16,24) t5->t6
  //   [24,26) WqT t2->t3   [26,30) WkvT t2->t4   [30,32) WprojT t2->t7
  //   [32,48) Qb  t3->t6   [48,56) AOb t6->t7
  char* ws = (char*)d_ws;
  u16* xb     = (u16*)(ws);
  u16* Kb     = (u16*)(ws);
  u16* Vb     = (u16*)(ws + (size_t)( 8<<20));
  u16* yb     = (u16*)(ws + (size_t)(16<<20));
  u16* Vtg    = (u16*)(ws + (size_t)(16<<20));
  u16* WqT    = (u16*)(ws + (size_t)(24<<20));
  u16* WkvT   = (u16*)(ws + (size_t)(26<<20));
  u16* WprojT = (u16*)(ws + (size_t)(30<<20));
  u16* Qb     = (u16*)(ws + (size_t)(32<<20));
  u16* AOb    = (u16*)(ws + (size_t)(48<<20));

  const dim3 tb(32, 8);
  cvt_bf16<<<dim3(4096), 256, 0, stream>>>(x, xb, B_*N_*DIM_);
  cvt_bf16<<<dim3(2048), 256, 0, stream>>>(y, yb, B_*N2_*DIM_);
  transpose_w<<<dim3(32, 32), tb, 0, stream>>>(Wq,    WqT,    1024, 1024);
  transpose_w<<<dim3(64, 32), tb, 0, stream>>>(Wkv,   WkvT,   1024, 2048);
  transpose_w<<<dim3(32, 32), tb, 0, stream>>>(Wproj, WprojT, 1024, 1024);

  // Q = (x @ Wq) * SCALE*log2e
  gemm_bt<1><<<dim3( 8, 64), 256, 0, stream>>>(xb, WqT, SCALE_*LOG2E_, nullptr,
                                               Qb, nullptr, 1024, 8192, 1024);
  // [K|V] = y @ Wkv, split into Kb / Vb
  gemm_bt<1><<<dim3(16, 32), 256, 0, stream>>>(yb, WkvT, 1.0f, nullptr,
                                               Kb, Vb, 1024, 4096, 1024);
  transpose_v<<<dim3(32, 2, 64), tb, 0, stream>>>(Vb, Vtg);
  attn2<<<dim3(64, 8), 512, 0, stream>>>(Qb, Kb, Vtg, pad, AOb);
  // out = AO @ Wproj + bproj  (f32)
  gemm_bt<0><<<dim3( 8, 64), 256, 0, stream>>>(AOb, WprojT, 1.0f, bproj,
                                               d_out, nullptr, 1024, 8192, 1024);
}